// Round 12
// baseline (384.328 us; speedup 1.0000x reference)
//
#include <hip/hip_runtime.h>
#include <hip/hip_bf16.h>
#include <stdint.h>

// out[m][n] = sum_k x[m][k] * centroids[idx[n][k]] + bias[n]
// M=8192, N=4096, K=4096. decode W->bf16, cvt x->bf16, then 256x256 MFMA GEMM.
// Round 12: 4 waves (2x2) of 128x128 each — halves per-CU ds_read demand
// (128 b128/tile vs 192) so the kernel becomes MFMA-bound. A dbuf 64 KiB,
// B TRIPLE-buffered 96 KiB (kills the B-stage WAR window). Same swizzle,
// staging primitive, 1 barrier/K-tile, counted lgkm/vmcnt as r6.

typedef unsigned short u16;
typedef __attribute__((ext_vector_type(8))) short short8;   // bf16x8 (4 VGPR)
typedef __attribute__((ext_vector_type(8))) u16   u16x8;
typedef __attribute__((ext_vector_type(4))) float f32x4;
typedef __attribute__((ext_vector_type(4))) int   i32x4;

constexpr int Mdim = 8192;
constexpr int Ndim = 4096;
constexpr int Kdim = 4096;

__device__ __forceinline__ u16 f2bf(float f) {
  union { float f; uint32_t u; } v; v.f = f;
  uint32_t u = v.u;
  return (u16)((u + 0x7fffu + ((u >> 16) & 1u)) >> 16);
}

// ---------------- decode: weight_bf16[n*K + k] = bf16(cent[idx[n*K + k]]) ----
__global__ void decode_weight_kernel(const int* __restrict__ idx,
                                     const float* __restrict__ cent,
                                     u16* __restrict__ wb) {
  __shared__ u16 lut[256];
  const int t = threadIdx.x;
  if (t < 256) lut[t] = f2bf(cent[t]);
  __syncthreads();
  const size_t base = ((size_t)blockIdx.x * 256 + t) * 8;
  i32x4 i0 = *(const i32x4*)(idx + base);
  i32x4 i1 = *(const i32x4*)(idx + base + 4);
  u16x8 r;
  r[0] = lut[i0[0] & 255]; r[1] = lut[i0[1] & 255];
  r[2] = lut[i0[2] & 255]; r[3] = lut[i0[3] & 255];
  r[4] = lut[i1[0] & 255]; r[5] = lut[i1[1] & 255];
  r[6] = lut[i1[2] & 255]; r[7] = lut[i1[3] & 255];
  *(u16x8*)(wb + base) = r;
}

// ---------------- convert: x fp32 -> bf16 -----------------------------------
__global__ void cvt_x_kernel(const float* __restrict__ x, u16* __restrict__ xb) {
  const size_t base = ((size_t)blockIdx.x * 256 + threadIdx.x) * 8;
  f32x4 a = *(const f32x4*)(x + base);
  f32x4 b = *(const f32x4*)(x + base + 4);
  u16x8 r;
  r[0] = f2bf(a[0]); r[1] = f2bf(a[1]); r[2] = f2bf(a[2]); r[3] = f2bf(a[3]);
  r[4] = f2bf(b[0]); r[5] = f2bf(b[1]); r[6] = f2bf(b[2]); r[7] = f2bf(b[3]);
  *(u16x8*)(xb + base) = r;
}

// ---------------- async 16B global -> LDS -----------------------------------
__device__ __forceinline__ void async16(const u16* g, u16* l) {
  __builtin_amdgcn_global_load_lds(
      (const __attribute__((address_space(1))) void*)g,
      (__attribute__((address_space(3))) void*)l,
      16, 0, 0);
}

#define BAR()    __builtin_amdgcn_s_barrier()
#define SCB()    __builtin_amdgcn_sched_barrier(0)
#define LGKM0()  do { asm volatile("s_waitcnt lgkmcnt(0)"  ::: "memory"); SCB(); } while (0)
#define LGKM4()  do { asm volatile("s_waitcnt lgkmcnt(4)"  ::: "memory"); SCB(); } while (0)
#define LGKM12() do { asm volatile("s_waitcnt lgkmcnt(12)" ::: "memory"); SCB(); } while (0)
#define VMC8()   asm volatile("s_waitcnt vmcnt(8)" ::: "memory")
#define VMC0()   asm volatile("s_waitcnt vmcnt(0)" ::: "memory")

// ---------------- 256x256 bf16 GEMM, 4 waves of 128x128, 1 barrier/K-tile ---
// 256 threads = 4 waves (2x2). BK=64. LDS: A 2 bufs x 32 KiB + B 3 bufs x
// 32 KiB = 160 KiB. Tile layout per 256x64 operand buffer: subtile (r16 =
// row>>4, kk = col>>5) at (r16*1024 + kk*512); within: fr*32 + swizzled quad
// (quad slot = (col>>3) ^ ((row>>1)&3)) — 0 bank conflicts (verified r3).
// Per wave/K-tile: 32 ds_read_b128, 128 MFMA; per-phase counted lgkm waits;
// one vmcnt(8)+s_barrier per tile. B(T+2) stages into buf (T+2)%3 (no WAR).
__global__ __launch_bounds__(256, 1)
void gemm_bf16_kernel(const u16* __restrict__ A,   // [Mdim][Kdim] bf16
                      const u16* __restrict__ B,   // [Ndim][Kdim] bf16
                      const float* __restrict__ bias,
                      float* __restrict__ C) {
  __shared__ u16 AsF[32768];   // 2 bufs x 16384 elems
  __shared__ u16 BsF[49152];   // 3 bufs x 16384 elems

  const int t    = threadIdx.x;
  const int lane = t & 63;
  const int w    = t >> 6;      // wave 0..3
  const int wr   = w >> 1;      // 0..1 -> A rows wr*128..+127
  const int wc   = w & 1;       // 0..1 -> B rows wc*128..+127
  const int fr   = lane & 15;
  const int fq   = lane >> 4;
  const int cswz = (fr & 6) << 2;   // ((fr>>1)&3)*8

  // T1: XCD-aware block swizzle (512 blocks, 512%8==0)
  const int bid = blockIdx.x;
  const int swz = (bid & 7) * 64 + (bid >> 3);
  const int m0 = (swz >> 4) * 256;   // 32 M-tiles
  const int n0 = (swz & 15) * 256;   // 16 N-tiles

  // staging: 256x64 tile = 2048 chunks of 16 B; thread t takes c = t + L*256,
  // L=0..7. c bits: [1:0]=quad [5:2]=r16-low [6]=kk [10:7]=row-group.
  // LDS dest elem = c*8 (linear); source col pre-swizzled.
  int srcOff[8];
#pragma unroll
  for (int L = 0; L < 8; ++L) {
    const int c    = t + L * 256;
    const int r16s = (c & 63) >> 2;
    const int srow = ((c >> 7) << 4) + r16s;            // 0..255
    const int scol = ((c >> 6) & 1) * 32 + (((c & 3) * 8) ^ ((r16s & 6) << 2));
    srcOff[L] = srow * Kdim + scol;
  }
  const u16* pA = A + (size_t)m0 * Kdim;
  const u16* pB = B + (size_t)n0 * Kdim;

  // fragment bases: elem(row r, col k) = (r>>4)*1024 + (k>>5)*512 +
  //   (r&15)*32 + (((k>>3)&3)^((r>>1)&3))*8 + (k&7)
  const int aBase = fr * 32 + ((fq * 8) ^ cswz);
  const int bBase = fr * 32 + ((fq * 8) ^ cswz);

  f32x4 acc[8][8] = {};
  short8 afE[8], afO[8];              // A frags kk0 / kk1 (8 mi each)
  short8 bE0[4], bE1[4], bO0[4], bO1[4];  // B frags (kk, ni-half)

  auto stA = [&](int tk, int buf, int L) {
    async16(pA + srcOff[L] + tk * 64, &AsF[(buf << 14) + t * 8 + L * 2048]);
  };
  auto stB = [&](int tk, int buf, int L) {
    async16(pB + srcOff[L] + tk * 64, &BsF[buf * 16384 + t * 8 + L * 2048]);
  };
  auto rdA = [&](short8 (&bk)[8], int buf, int kk) {
#pragma unroll
    for (int mi = 0; mi < 8; ++mi)
      bk[mi] = *(const short8*)&AsF[(buf << 14) + (wr * 8 + mi) * 1024 + kk * 512 + aBase];
  };
  auto rdB = [&](short8 (&bk)[4], int buf, int kk, int nh) {
#pragma unroll
    for (int j = 0; j < 4; ++j)
      bk[j] = *(const short8*)&BsF[buf * 16384 + (wc * 8 + nh * 4 + j) * 1024 + kk * 512 + bBase];
  };
  auto mfmaLo = [&](short8 (&a)[8], short8 (&b)[4]) {   // acc[*][0..3]
#pragma unroll
    for (int mi = 0; mi < 8; ++mi)
#pragma unroll
      for (int j = 0; j < 4; ++j)
        acc[mi][j] = __builtin_amdgcn_mfma_f32_16x16x32_bf16(
            a[mi], b[j], acc[mi][j], 0, 0, 0);
  };
  auto mfmaHi = [&](short8 (&a)[8], short8 (&b)[4]) {   // acc[*][4..7]
#pragma unroll
    for (int mi = 0; mi < 8; ++mi)
#pragma unroll
      for (int j = 0; j < 4; ++j)
        acc[mi][4 + j] = __builtin_amdgcn_mfma_f32_16x16x32_bf16(
            a[mi], b[j], acc[mi][4 + j], 0, 0, 0);
  };

  // Tile T. Entry: boundary 12 ds_reads (afE 8 + bE0 4) in flight;
  // vm outstanding = 8 = B(T+1). ABUF=T&1, BCUR=T%3, BNXT=(T+1)%3,
  // BST=(T+2)%3. MODE: 0 normal; 1 = tile 62 (no B stage, drain); 2 = last.
#define KT(TK, ABUF, BCUR, BNXT, BST, MODE)                              \
  {                                                                      \
    /* ph0: kk0 x ni(0..3) */                                            \
    rdB(bE1, (BCUR), 0, 1);                                              \
    if ((MODE) < 2) { stA((TK) + 1, (ABUF) ^ 1, 0); stA((TK) + 1, (ABUF) ^ 1, 1); \
                      stA((TK) + 1, (ABUF) ^ 1, 2); stA((TK) + 1, (ABUF) ^ 1, 3); } \
    LGKM4();                  /* boundary 12 done */                     \
    mfmaLo(afE, bE0);                                                    \
    /* ph1: kk0 x ni(4..7) */                                            \
    rdA(afO, (ABUF), 1); rdB(bO0, (BCUR), 1, 0);                         \
    if ((MODE) < 2) { stA((TK) + 1, (ABUF) ^ 1, 4); stA((TK) + 1, (ABUF) ^ 1, 5); \
                      stA((TK) + 1, (ABUF) ^ 1, 6); stA((TK) + 1, (ABUF) ^ 1, 7); } \
    if ((MODE) == 0) { stB((TK) + 2, (BST), 0); stB((TK) + 2, (BST), 1); } \
    LGKM12();                 /* bE1 done */                             \
    mfmaHi(afE, bE1);                                                    \
    /* ph2: kk1 x ni(0..3) */                                            \
    rdB(bO1, (BCUR), 1, 1);                                              \
    if ((MODE) == 0) { stB((TK) + 2, (BST), 2); stB((TK) + 2, (BST), 3); \
                       stB((TK) + 2, (BST), 4); stB((TK) + 2, (BST), 5); } \
    LGKM4();                  /* afO + bO0 done */                       \
    mfmaLo(afO, bO0);                                                    \
    /* ph3: kk1 x ni(4..7) + the one sync point */                       \
    if ((MODE) == 0) { stB((TK) + 2, (BST), 6); stB((TK) + 2, (BST), 7); } \
    if ((MODE) == 0) { VMC8(); BAR(); }                                  \
    else if ((MODE) == 1) { VMC0(); BAR(); }                             \
    if ((MODE) < 2) { rdA(afE, (ABUF) ^ 1, 0); rdB(bE0, (BNXT), 0, 0);   \
                      LGKM12(); }   /* bO1 done; boundary in flight */   \
    else { LGKM0(); }                                                    \
    mfmaHi(afO, bO1);                                                    \
  }

  // Prologue: stage A(0)->A0, B(0)->B0, B(1)->B1 (24 loads); VMC8 leaves
  // B(1)=8 in flight; barrier; boundary reads for tile 0.
#pragma unroll
  for (int L = 0; L < 8; ++L) stA(0, 0, L);
#pragma unroll
  for (int L = 0; L < 8; ++L) stB(0, 0, L);
#pragma unroll
  for (int L = 0; L < 8; ++L) stB(1, 1, L);
  VMC8();
  BAR();
  rdA(afE, 0, 0);
  rdB(bE0, 0, 0, 0);

  for (int t6 = 0; t6 < 60; t6 += 6) {    // K-tiles 0..59
    KT(t6 + 0, 0, 0, 1, 2, 0);
    KT(t6 + 1, 1, 1, 2, 0, 0);
    KT(t6 + 2, 0, 2, 0, 1, 0);
    KT(t6 + 3, 1, 0, 1, 2, 0);
    KT(t6 + 4, 0, 1, 2, 0, 0);
    KT(t6 + 5, 1, 2, 0, 1, 0);
  }
  KT(60, 0, 0, 1, 2, 0);                  // stages A(61), B(62)
  KT(61, 1, 1, 2, 0, 0);                  // stages A(62), B(63)
  KT(62, 0, 2, 0, 0, 1);                  // stages A(63); drain vm
  KT(63, 1, 0, 0, 0, 2);                  // last

  // Epilogue: C/D map col=lane&15, row=(lane>>4)*4+j  [m89, r6-verified]
  float bv[8];
#pragma unroll
  for (int ni = 0; ni < 8; ++ni)
    bv[ni] = bias[n0 + wc * 128 + ni * 16 + fr];

#pragma unroll
  for (int mi = 0; mi < 8; ++mi) {
#pragma unroll
    for (int j = 0; j < 4; ++j) {
      const int row = m0 + wr * 128 + mi * 16 + fq * 4 + j;
      float* cp = C + (size_t)row * Ndim + n0 + wc * 128 + fr;
#pragma unroll
      for (int ni = 0; ni < 8; ++ni)
        cp[ni * 16] = acc[mi][ni][j] + bv[ni];
    }
  }
#undef KT
}

extern "C" void kernel_launch(void* const* d_in, const int* in_sizes, int n_in,
                              void* d_out, int out_size, void* d_ws, size_t ws_size,
                              hipStream_t stream) {
  const float* x    = (const float*)d_in[0];   // [8192][4096] fp32
  const float* cent = (const float*)d_in[1];   // [256] fp32
  const float* bias = (const float*)d_in[2];   // [4096] fp32
  const int*   idx  = (const int*)d_in[3];     // [4096][4096] int
  float* out = (float*)d_out;                  // [8192][4096] fp32

  u16* wb = (u16*)d_ws;
  u16* xb = (u16*)((char*)d_ws + (size_t)Ndim * Kdim * sizeof(u16));

  decode_weight_kernel<<<(Ndim * Kdim) / (256 * 8), 256, 0, stream>>>(idx, cent, wb);
  cvt_x_kernel<<<((size_t)Mdim * Kdim) / (256 * 8), 256, 0, stream>>>(x, xb);

  gemm_bf16_kernel<<<dim3(512), 256, 0, stream>>>(xb, wb, bias, out);
}

// Round 14
// 278.906 us; speedup vs baseline: 1.3780x; 1.3780x over previous
//
#include <hip/hip_runtime.h>
#include <hip/hip_bf16.h>
#include <stdint.h>

// out[m][n] = sum_k x[m][k] * centroids[idx[n][k]] + bias[n]
// M=8192, N=4096, K=4096. Round 14: champion r6 GEMM (256x256, 8 waves,
// 1 barrier/K-tile, counted lgkm, vmcnt(4), 0-conflict swizzle) + merged
// decode/cvt pre-pass (one launch instead of two).

typedef unsigned short u16;
typedef __attribute__((ext_vector_type(8))) short short8;   // bf16x8 (4 VGPR)
typedef __attribute__((ext_vector_type(8))) u16   u16x8;
typedef __attribute__((ext_vector_type(4))) float f32x4;
typedef __attribute__((ext_vector_type(4))) int   i32x4;

constexpr int Mdim = 8192;
constexpr int Ndim = 4096;
constexpr int Kdim = 4096;

__device__ __forceinline__ u16 f2bf(float f) {
  union { float f; uint32_t u; } v; v.f = f;
  uint32_t u = v.u;
  return (u16)((u + 0x7fffu + ((u >> 16) & 1u)) >> 16);
}

// ---------------- merged pre-pass ------------------------------------------
// blocks [0, 8192): decode weight_bf16[n*K+k] = bf16(cent[idx[n*K+k]])
// blocks [8192, 24576): cvt x fp32 -> bf16
__global__ void prep_kernel(const int* __restrict__ idx,
                            const float* __restrict__ cent,
                            const float* __restrict__ x,
                            u16* __restrict__ wb,
                            u16* __restrict__ xb) {
  const int t = threadIdx.x;
  if (blockIdx.x < 8192) {
    __shared__ u16 lut[256];
    if (t < 256) lut[t] = f2bf(cent[t]);
    __syncthreads();
    const size_t base = ((size_t)blockIdx.x * 256 + t) * 8;
    i32x4 i0 = *(const i32x4*)(idx + base);
    i32x4 i1 = *(const i32x4*)(idx + base + 4);
    u16x8 r;
    r[0] = lut[i0[0] & 255]; r[1] = lut[i0[1] & 255];
    r[2] = lut[i0[2] & 255]; r[3] = lut[i0[3] & 255];
    r[4] = lut[i1[0] & 255]; r[5] = lut[i1[1] & 255];
    r[6] = lut[i1[2] & 255]; r[7] = lut[i1[3] & 255];
    *(u16x8*)(wb + base) = r;
  } else {
    const size_t base = ((size_t)(blockIdx.x - 8192) * 256 + t) * 8;
    f32x4 a = *(const f32x4*)(x + base);
    f32x4 b = *(const f32x4*)(x + base + 4);
    u16x8 r;
    r[0] = f2bf(a[0]); r[1] = f2bf(a[1]); r[2] = f2bf(a[2]); r[3] = f2bf(a[3]);
    r[4] = f2bf(b[0]); r[5] = f2bf(b[1]); r[6] = f2bf(b[2]); r[7] = f2bf(b[3]);
    *(u16x8*)(xb + base) = r;
  }
}

// ---------------- async 16B global -> LDS -----------------------------------
__device__ __forceinline__ void async16(const u16* g, u16* l) {
  __builtin_amdgcn_global_load_lds(
      (const __attribute__((address_space(1))) void*)g,
      (__attribute__((address_space(3))) void*)l,
      16, 0, 0);
}

#define BAR()   __builtin_amdgcn_s_barrier()
#define SCB()   __builtin_amdgcn_sched_barrier(0)
#define LGKM0() do { asm volatile("s_waitcnt lgkmcnt(0)" ::: "memory"); SCB(); } while (0)
#define LGKM4() do { asm volatile("s_waitcnt lgkmcnt(4)" ::: "memory"); SCB(); } while (0)
#define VMC4()  asm volatile("s_waitcnt vmcnt(4)" ::: "memory")
#define VMC0()  asm volatile("s_waitcnt vmcnt(0)" ::: "memory")

// ---------------- 256x256 bf16 GEMM, 1 barrier per K-tile (r6, verified) ----
// 512 threads = 8 waves (2 M-waves x 4 N-waves). BK=64, dbuf LDS 128 KiB.
// LDS per half: 16x32-elem subtiles (1 KiB); quad slot = (col>>3) ^ ((r>>1)&3)
// (0 bank conflicts, verified r3). Per-wave ds_reads pipelined one phase
// ahead with counted lgkmcnt; cross-wave sync only at the K-tile boundary:
// vmcnt(4) [A(T+1),B(T+1) landed; B(T+2) stays in flight] + s_barrier.
__global__ __launch_bounds__(512, 2)
void gemm_bf16_kernel(const u16* __restrict__ A,   // [Mdim][Kdim] bf16
                      const u16* __restrict__ B,   // [Ndim][Kdim] bf16
                      const float* __restrict__ bias,
                      float* __restrict__ C) {
  __shared__ u16 AsF[32768];   // [buf][half][8192 elems] = 64 KiB
  __shared__ u16 BsF[32768];

  const int t    = threadIdx.x;
  const int lane = t & 63;
  const int w    = t >> 6;      // wave 0..7
  const int wm   = w >> 2;      // 0..1  -> A rows wm*128..+127
  const int wn   = w & 3;       // 0..3  -> B rows wn*64..+63
  const int fr   = lane & 15;
  const int fq   = lane >> 4;
  const int cswz = (fr & 6) << 2;   // ((fr>>1)&3)*8

  // T1: XCD-aware block swizzle (512 blocks, 512%8==0 -> simple form OK)
  const int bid = blockIdx.x;
  const int swz = (bid & 7) * 64 + (bid >> 3);
  const int m0 = (swz >> 4) * 256;   // 32 M-tiles
  const int n0 = (swz & 15) * 256;   // 16 N-tiles

  // staging geometry: chunk c = l*512 + w*64 + lane (16 B each), LDS linear.
  const int c0   = w * 64 + lane;                    // chunk for l=0
  const int r16s = (c0 & 63) >> 2;
  const int srow = ((c0 >> 7) << 4) + r16s;          // 0..63 (l=1 -> +64)
  const int scol = ((c0 >> 6) & 1) * 32 + (((c0 & 3) * 8) ^ ((r16s & 6) << 2));
  const u16* pA = A + (size_t)(m0 + srow) * Kdim + scol;
  const u16* pB = B + (size_t)(n0 + srow) * Kdim + scol;
  const int dsto = c0 * 8;                           // LDS elem offset

  // fragment read offsets (elements): (rt*2+kk)*512 + fr*32 + swizzled col
  const int aoff = wm * 8192 + fr * 32 + ((fq * 8) ^ cswz);
  const int boff = (wn >> 1) * 8192 + (wn & 1) * 4096 + fr * 32 + ((fq * 8) ^ cswz);

  f32x4 acc[8][4] = {};
  short8 bf[2][4];      // [kk][ni], refreshed at tile boundary
  short8 afA[2][2];     // even-q A frags (q0, q2)
  short8 afB[2][2];     // odd-q  A frags (q1, q3)

  auto stageA = [&](int tk, int h) {
    const u16* s = pA + (size_t)h * (128 * Kdim) + tk * 64;
    u16* d = &AsF[((tk & 1) * 2 + h) * 8192 + dsto];
    async16(s, d);
    async16(s + (size_t)(64 * Kdim), d + 4096);
  };
  auto stageB = [&](int tk, int h) {
    const u16* s = pB + (size_t)h * (128 * Kdim) + tk * 64;
    u16* d = &BsF[((tk & 1) * 2 + h) * 8192 + dsto];
    async16(s, d);
    async16(s + (size_t)(64 * Kdim), d + 4096);
  };
  auto rdB_kk = [&](int buf, int kk) {
#pragma unroll
    for (int ni = 0; ni < 4; ++ni)
      bf[kk][ni] = *(const short8*)&BsF[buf * 16384 + boff + (ni * 2 + kk) * 512];
  };
  auto rdA_A = [&](int buf, int q) {
#pragma unroll
    for (int kk = 0; kk < 2; ++kk)
#pragma unroll
      for (int i = 0; i < 2; ++i)
        afA[kk][i] = *(const short8*)&AsF[buf * 16384 + aoff + ((q * 2 + i) * 2 + kk) * 512];
  };
  auto rdA_B = [&](int buf, int q) {
#pragma unroll
    for (int kk = 0; kk < 2; ++kk)
#pragma unroll
      for (int i = 0; i < 2; ++i)
        afB[kk][i] = *(const short8*)&AsF[buf * 16384 + aoff + ((q * 2 + i) * 2 + kk) * 512];
  };
  auto mfmaE = [&](int q) {   // uses afA
    __builtin_amdgcn_s_setprio(1);
#pragma unroll
    for (int kk = 0; kk < 2; ++kk)
#pragma unroll
      for (int i = 0; i < 2; ++i)
#pragma unroll
        for (int ni = 0; ni < 4; ++ni)
          acc[q * 2 + i][ni] = __builtin_amdgcn_mfma_f32_16x16x32_bf16(
              afA[kk][i], bf[kk][ni], acc[q * 2 + i][ni], 0, 0, 0);
    __builtin_amdgcn_s_setprio(0);
  };
  auto mfmaO = [&](int q) {   // uses afB
    __builtin_amdgcn_s_setprio(1);
#pragma unroll
    for (int kk = 0; kk < 2; ++kk)
#pragma unroll
      for (int i = 0; i < 2; ++i)
#pragma unroll
        for (int ni = 0; ni < 4; ++ni)
          acc[q * 2 + i][ni] = __builtin_amdgcn_mfma_f32_16x16x32_bf16(
              afB[kk][i], bf[kk][ni], acc[q * 2 + i][ni], 0, 0, 0);
    __builtin_amdgcn_s_setprio(0);
  };
  auto mfmaO_kk = [&](int q, int kk) {   // one kk-half of an odd q
    __builtin_amdgcn_s_setprio(1);
#pragma unroll
    for (int i = 0; i < 2; ++i)
#pragma unroll
      for (int ni = 0; ni < 4; ++ni)
        acc[q * 2 + i][ni] = __builtin_amdgcn_mfma_f32_16x16x32_bf16(
            afB[kk][i], bf[kk][ni], acc[q * 2 + i][ni], 0, 0, 0);
    __builtin_amdgcn_s_setprio(0);
  };

  // Tile T (BUF=T&1). Entry invariant (per wave): afA=q0 frags, bf=B(T);
  // 12 boundary ds_reads in flight; B(T+1)=4 vmem outstanding.
  // MODE: 0 normal (vmcnt(4)); 1 tile 62 (no B stage, vmcnt(0)); 2 last.
#define KT(TK, BUF, DOA, DOB, MODE)                                     \
  {                                                                     \
    /* p0 */                                                            \
    rdA_B((BUF), 1);                                                    \
    if (DOA) stageA((TK) + 1, 0);                                       \
    LGKM4();                 /* boundary 12 done; q1 reads in flight */ \
    mfmaE(0);                                                           \
    /* p1 */                                                            \
    rdA_A((BUF), 2);                                                    \
    if (DOA) stageA((TK) + 1, 1);                                       \
    if (DOB) stageB((TK) + 2, 0);                                       \
    LGKM4();                 /* q1 done */                              \
    mfmaO(1);                                                           \
    /* p2 */                                                            \
    rdA_B((BUF), 3);                                                    \
    if (DOB) stageB((TK) + 2, 1);                                       \
    LGKM4();                 /* q2 done */                              \
    mfmaE(2);                                                           \
    /* p3: the one cross-wave sync point per K-tile */                  \
    if ((MODE) == 0) { VMC4(); } else if ((MODE) == 1) { VMC0(); }      \
    BAR();                   /* all waves: A(T+1)/B(T+1) landed */      \
    LGKM0();                 /* q3 reads done */                        \
    mfmaO_kk(3, 0);                                                     \
    if ((MODE) < 2) rdB_kk((BUF) ^ 1, 0);                               \
    mfmaO_kk(3, 1);                                                     \
    if ((MODE) < 2) { rdB_kk((BUF) ^ 1, 1); rdA_A((BUF) ^ 1, 0); }      \
  }

  // Prologue: stage A(0),B(0),B(1); vmcnt(4) leaves B(1) in flight; barrier;
  // boundary reads for tile 0.
  stageA(0, 0); stageA(0, 1); stageB(0, 0); stageB(0, 1);
  stageB(1, 0); stageB(1, 1);
  VMC4();
  BAR();
  rdB_kk(0, 0); rdB_kk(0, 1); rdA_A(0, 0);

  for (int t2 = 0; t2 < 31; ++t2) {       // K-tiles 0..61
    const int k0 = 2 * t2;
    KT(k0,     0, 1, 1, 0);
    KT(k0 + 1, 1, 1, 1, 0);
  }
  KT(62, 0, 1, 0, 1);                     // stage A(63); drain vmcnt to 0
  KT(63, 1, 0, 0, 2);                     // last: no staging, no boundary

  // Epilogue: C/D map col=lane&15, row=(lane>>4)*4+j  [m89]
  float bv[4];
#pragma unroll
  for (int ni = 0; ni < 4; ++ni)
    bv[ni] = bias[n0 + wn * 64 + ni * 16 + fr];

#pragma unroll
  for (int mi = 0; mi < 8; ++mi) {
#pragma unroll
    for (int j = 0; j < 4; ++j) {
      const int row = m0 + wm * 128 + mi * 16 + fq * 4 + j;
      float* cp = C + (size_t)row * Ndim + n0 + wn * 64 + fr;
#pragma unroll
      for (int ni = 0; ni < 4; ++ni)
        cp[ni * 16] = acc[mi][ni][j] + bv[ni];
    }
  }
#undef KT
}

extern "C" void kernel_launch(void* const* d_in, const int* in_sizes, int n_in,
                              void* d_out, int out_size, void* d_ws, size_t ws_size,
                              hipStream_t stream) {
  const float* x    = (const float*)d_in[0];   // [8192][4096] fp32
  const float* cent = (const float*)d_in[1];   // [256] fp32
  const float* bias = (const float*)d_in[2];   // [4096] fp32
  const int*   idx  = (const int*)d_in[3];     // [4096][4096] int
  float* out = (float*)d_out;                  // [8192][4096] fp32

  u16* wb = (u16*)d_ws;
  u16* xb = (u16*)((char*)d_ws + (size_t)Ndim * Kdim * sizeof(u16));

  prep_kernel<<<dim3(24576), 256, 0, stream>>>(idx, cent, x, wb, xb);
  gemm_bf16_kernel<<<dim3(512), 512, 0, stream>>>(xb, wb, bias, out);
}

// Round 16
// 270.359 us; speedup vs baseline: 1.4215x; 1.0316x over previous
//
#include <hip/hip_runtime.h>
#include <hip/hip_bf16.h>
#include <stdint.h>

// out[m][n] = sum_k x[m][k] * centroids[idx[n][k]] + bias[n]
// M=8192, N=4096, K=4096. Round 16: REVERT to r14 champion (r6 GEMM + merged
// prep). r15's tweak (B-stage issued before the wave's own LGKM4 that drains
// the boundary rdB_kk of the same buffer) raced — the r6 issue order
// (stage writes strictly after the lgkm wait that retires reads of the
// target buffer) is a correctness constraint. Do not reorder.

typedef unsigned short u16;
typedef __attribute__((ext_vector_type(8))) short short8;   // bf16x8 (4 VGPR)
typedef __attribute__((ext_vector_type(8))) u16   u16x8;
typedef __attribute__((ext_vector_type(4))) float f32x4;
typedef __attribute__((ext_vector_type(4))) int   i32x4;

constexpr int Mdim = 8192;
constexpr int Ndim = 4096;
constexpr int Kdim = 4096;

__device__ __forceinline__ u16 f2bf(float f) {
  union { float f; uint32_t u; } v; v.f = f;
  uint32_t u = v.u;
  return (u16)((u + 0x7fffu + ((u >> 16) & 1u)) >> 16);
}

// ---------------- merged pre-pass ------------------------------------------
// blocks [0, 8192): decode weight_bf16[n*K+k] = bf16(cent[idx[n*K+k]])
// blocks [8192, 24576): cvt x fp32 -> bf16
__global__ void prep_kernel(const int* __restrict__ idx,
                            const float* __restrict__ cent,
                            const float* __restrict__ x,
                            u16* __restrict__ wb,
                            u16* __restrict__ xb) {
  const int t = threadIdx.x;
  if (blockIdx.x < 8192) {
    __shared__ u16 lut[256];
    if (t < 256) lut[t] = f2bf(cent[t]);
    __syncthreads();
    const size_t base = ((size_t)blockIdx.x * 256 + t) * 8;
    i32x4 i0 = *(const i32x4*)(idx + base);
    i32x4 i1 = *(const i32x4*)(idx + base + 4);
    u16x8 r;
    r[0] = lut[i0[0] & 255]; r[1] = lut[i0[1] & 255];
    r[2] = lut[i0[2] & 255]; r[3] = lut[i0[3] & 255];
    r[4] = lut[i1[0] & 255]; r[5] = lut[i1[1] & 255];
    r[6] = lut[i1[2] & 255]; r[7] = lut[i1[3] & 255];
    *(u16x8*)(wb + base) = r;
  } else {
    const size_t base = ((size_t)(blockIdx.x - 8192) * 256 + t) * 8;
    f32x4 a = *(const f32x4*)(x + base);
    f32x4 b = *(const f32x4*)(x + base + 4);
    u16x8 r;
    r[0] = f2bf(a[0]); r[1] = f2bf(a[1]); r[2] = f2bf(a[2]); r[3] = f2bf(a[3]);
    r[4] = f2bf(b[0]); r[5] = f2bf(b[1]); r[6] = f2bf(b[2]); r[7] = f2bf(b[3]);
    *(u16x8*)(xb + base) = r;
  }
}

// ---------------- async 16B global -> LDS -----------------------------------
__device__ __forceinline__ void async16(const u16* g, u16* l) {
  __builtin_amdgcn_global_load_lds(
      (const __attribute__((address_space(1))) void*)g,
      (__attribute__((address_space(3))) void*)l,
      16, 0, 0);
}

#define BAR()   __builtin_amdgcn_s_barrier()
#define SCB()   __builtin_amdgcn_sched_barrier(0)
#define LGKM0() do { asm volatile("s_waitcnt lgkmcnt(0)" ::: "memory"); SCB(); } while (0)
#define LGKM4() do { asm volatile("s_waitcnt lgkmcnt(4)" ::: "memory"); SCB(); } while (0)
#define VMC4()  asm volatile("s_waitcnt vmcnt(4)" ::: "memory")
#define VMC0()  asm volatile("s_waitcnt vmcnt(0)" ::: "memory")

// ---------------- 256x256 bf16 GEMM, 1 barrier per K-tile (r6, verified) ----
// 512 threads = 8 waves (2 M-waves x 4 N-waves). BK=64, dbuf LDS 128 KiB.
// LDS per half: 16x32-elem subtiles (1 KiB); quad slot = (col>>3) ^ ((r>>1)&3)
// (0 bank conflicts, verified r3). Per-wave ds_reads pipelined one phase
// ahead with counted lgkmcnt; cross-wave sync only at the K-tile boundary:
// vmcnt(4) [A(T+1),B(T+1) landed; B(T+2) stays in flight] + s_barrier.
__global__ __launch_bounds__(512, 2)
void gemm_bf16_kernel(const u16* __restrict__ A,   // [Mdim][Kdim] bf16
                      const u16* __restrict__ B,   // [Ndim][Kdim] bf16
                      const float* __restrict__ bias,
                      float* __restrict__ C) {
  __shared__ u16 AsF[32768];   // [buf][half][8192 elems] = 64 KiB
  __shared__ u16 BsF[32768];

  const int t    = threadIdx.x;
  const int lane = t & 63;
  const int w    = t >> 6;      // wave 0..7
  const int wm   = w >> 2;      // 0..1  -> A rows wm*128..+127
  const int wn   = w & 3;       // 0..3  -> B rows wn*64..+63
  const int fr   = lane & 15;
  const int fq   = lane >> 4;
  const int cswz = (fr & 6) << 2;   // ((fr>>1)&3)*8

  // T1: XCD-aware block swizzle (512 blocks, 512%8==0 -> simple form OK)
  const int bid = blockIdx.x;
  const int swz = (bid & 7) * 64 + (bid >> 3);
  const int m0 = (swz >> 4) * 256;   // 32 M-tiles
  const int n0 = (swz & 15) * 256;   // 16 N-tiles

  // staging geometry: chunk c = l*512 + w*64 + lane (16 B each), LDS linear.
  const int c0   = w * 64 + lane;                    // chunk for l=0
  const int r16s = (c0 & 63) >> 2;
  const int srow = ((c0 >> 7) << 4) + r16s;          // 0..63 (l=1 -> +64)
  const int scol = ((c0 >> 6) & 1) * 32 + (((c0 & 3) * 8) ^ ((r16s & 6) << 2));
  const u16* pA = A + (size_t)(m0 + srow) * Kdim + scol;
  const u16* pB = B + (size_t)(n0 + srow) * Kdim + scol;
  const int dsto = c0 * 8;                           // LDS elem offset

  // fragment read offsets (elements): (rt*2+kk)*512 + fr*32 + swizzled col
  const int aoff = wm * 8192 + fr * 32 + ((fq * 8) ^ cswz);
  const int boff = (wn >> 1) * 8192 + (wn & 1) * 4096 + fr * 32 + ((fq * 8) ^ cswz);

  f32x4 acc[8][4] = {};
  short8 bf[2][4];      // [kk][ni], refreshed at tile boundary
  short8 afA[2][2];     // even-q A frags (q0, q2)
  short8 afB[2][2];     // odd-q  A frags (q1, q3)

  auto stageA = [&](int tk, int h) {
    const u16* s = pA + (size_t)h * (128 * Kdim) + tk * 64;
    u16* d = &AsF[((tk & 1) * 2 + h) * 8192 + dsto];
    async16(s, d);
    async16(s + (size_t)(64 * Kdim), d + 4096);
  };
  auto stageB = [&](int tk, int h) {
    const u16* s = pB + (size_t)h * (128 * Kdim) + tk * 64;
    u16* d = &BsF[((tk & 1) * 2 + h) * 8192 + dsto];
    async16(s, d);
    async16(s + (size_t)(64 * Kdim), d + 4096);
  };
  auto rdB_kk = [&](int buf, int kk) {
#pragma unroll
    for (int ni = 0; ni < 4; ++ni)
      bf[kk][ni] = *(const short8*)&BsF[buf * 16384 + boff + (ni * 2 + kk) * 512];
  };
  auto rdA_A = [&](int buf, int q) {
#pragma unroll
    for (int kk = 0; kk < 2; ++kk)
#pragma unroll
      for (int i = 0; i < 2; ++i)
        afA[kk][i] = *(const short8*)&AsF[buf * 16384 + aoff + ((q * 2 + i) * 2 + kk) * 512];
  };
  auto rdA_B = [&](int buf, int q) {
#pragma unroll
    for (int kk = 0; kk < 2; ++kk)
#pragma unroll
      for (int i = 0; i < 2; ++i)
        afB[kk][i] = *(const short8*)&AsF[buf * 16384 + aoff + ((q * 2 + i) * 2 + kk) * 512];
  };
  auto mfmaE = [&](int q) {   // uses afA
    __builtin_amdgcn_s_setprio(1);
#pragma unroll
    for (int kk = 0; kk < 2; ++kk)
#pragma unroll
      for (int i = 0; i < 2; ++i)
#pragma unroll
        for (int ni = 0; ni < 4; ++ni)
          acc[q * 2 + i][ni] = __builtin_amdgcn_mfma_f32_16x16x32_bf16(
              afA[kk][i], bf[kk][ni], acc[q * 2 + i][ni], 0, 0, 0);
    __builtin_amdgcn_s_setprio(0);
  };
  auto mfmaO = [&](int q) {   // uses afB
    __builtin_amdgcn_s_setprio(1);
#pragma unroll
    for (int kk = 0; kk < 2; ++kk)
#pragma unroll
      for (int i = 0; i < 2; ++i)
#pragma unroll
        for (int ni = 0; ni < 4; ++ni)
          acc[q * 2 + i][ni] = __builtin_amdgcn_mfma_f32_16x16x32_bf16(
              afB[kk][i], bf[kk][ni], acc[q * 2 + i][ni], 0, 0, 0);
    __builtin_amdgcn_s_setprio(0);
  };
  auto mfmaO_kk = [&](int q, int kk) {   // one kk-half of an odd q
    __builtin_amdgcn_s_setprio(1);
#pragma unroll
    for (int i = 0; i < 2; ++i)
#pragma unroll
      for (int ni = 0; ni < 4; ++ni)
        acc[q * 2 + i][ni] = __builtin_amdgcn_mfma_f32_16x16x32_bf16(
            afB[kk][i], bf[kk][ni], acc[q * 2 + i][ni], 0, 0, 0);
    __builtin_amdgcn_s_setprio(0);
  };

  // Tile T (BUF=T&1). Entry invariant (per wave): afA=q0 frags, bf=B(T);
  // 12 boundary ds_reads in flight; B(T+1)=4 vmem outstanding.
  // MODE: 0 normal (vmcnt(4)); 1 tile 62 (no B stage, vmcnt(0)); 2 last.
  // NOTE: stage issue positions are correctness-constrained (r15 lesson):
  // each stage write must follow the LGKM wait that retires this wave's
  // reads of the target buffer.
#define KT(TK, BUF, DOA, DOB, MODE)                                     \
  {                                                                     \
    /* p0 */                                                            \
    rdA_B((BUF), 1);                                                    \
    if (DOA) stageA((TK) + 1, 0);                                       \
    LGKM4();                 /* boundary 12 done; q1 reads in flight */ \
    mfmaE(0);                                                           \
    /* p1 */                                                            \
    rdA_A((BUF), 2);                                                    \
    if (DOA) stageA((TK) + 1, 1);                                       \
    if (DOB) stageB((TK) + 2, 0);                                       \
    LGKM4();                 /* q1 done */                              \
    mfmaO(1);                                                           \
    /* p2 */                                                            \
    rdA_B((BUF), 3);                                                    \
    if (DOB) stageB((TK) + 2, 1);                                       \
    LGKM4();                 /* q2 done */                              \
    mfmaE(2);                                                           \
    /* p3: the one cross-wave sync point per K-tile */                  \
    if ((MODE) == 0) { VMC4(); } else if ((MODE) == 1) { VMC0(); }      \
    BAR();                   /* all waves: A(T+1)/B(T+1) landed */      \
    LGKM0();                 /* q3 reads done */                        \
    mfmaO_kk(3, 0);                                                     \
    if ((MODE) < 2) rdB_kk((BUF) ^ 1, 0);                               \
    mfmaO_kk(3, 1);                                                     \
    if ((MODE) < 2) { rdB_kk((BUF) ^ 1, 1); rdA_A((BUF) ^ 1, 0); }      \
  }

  // Prologue: stage A(0),B(0),B(1); vmcnt(4) leaves B(1) in flight; barrier;
  // boundary reads for tile 0.
  stageA(0, 0); stageA(0, 1); stageB(0, 0); stageB(0, 1);
  stageB(1, 0); stageB(1, 1);
  VMC4();
  BAR();
  rdB_kk(0, 0); rdB_kk(0, 1); rdA_A(0, 0);

  for (int t2 = 0; t2 < 31; ++t2) {       // K-tiles 0..61
    const int k0 = 2 * t2;
    KT(k0,     0, 1, 1, 0);
    KT(k0 + 1, 1, 1, 1, 0);
  }
  KT(62, 0, 1, 0, 1);                     // stage A(63); drain vmcnt to 0
  KT(63, 1, 0, 0, 2);                     // last: no staging, no boundary

  // Epilogue: C/D map col=lane&15, row=(lane>>4)*4+j  [m89]
  float bv[4];
#pragma unroll
  for (int ni = 0; ni < 4; ++ni)
    bv[ni] = bias[n0 + wn * 64 + ni * 16 + fr];

#pragma unroll
  for (int mi = 0; mi < 8; ++mi) {
#pragma unroll
    for (int j = 0; j < 4; ++j) {
      const int row = m0 + wm * 128 + mi * 16 + fq * 4 + j;
      float* cp = C + (size_t)row * Ndim + n0 + wn * 64 + fr;
#pragma unroll
      for (int ni = 0; ni < 4; ++ni)
        cp[ni * 16] = acc[mi][ni][j] + bv[ni];
    }
  }
#undef KT
}

extern "C" void kernel_launch(void* const* d_in, const int* in_sizes, int n_in,
                              void* d_out, int out_size, void* d_ws, size_t ws_size,
                              hipStream_t stream) {
  const float* x    = (const float*)d_in[0];   // [8192][4096] fp32
  const float* cent = (const float*)d_in[1];   // [256] fp32
  const float* bias = (const float*)d_in[2];   // [4096] fp32
  const int*   idx  = (const int*)d_in[3];     // [4096][4096] int
  float* out = (float*)d_out;                  // [8192][4096] fp32

  u16* wb = (u16*)d_ws;
  u16* xb = (u16*)((char*)d_ws + (size_t)Ndim * Kdim * sizeof(u16));

  prep_kernel<<<dim3(24576), 256, 0, stream>>>(idx, cent, x, wb, xb);
  gemm_bf16_kernel<<<dim3(512), 512, 0, stream>>>(xb, wb, bias, out);
}